// Round 5
// baseline (141.122 us; speedup 1.0000x reference)
//
#include <hip/hip_runtime.h>
#include <math.h>

#define BB 512
#define SS 200
#define DD 512
#define KK 128

typedef __attribute__((ext_vector_type(8))) short bf16x8;
typedef __attribute__((ext_vector_type(4))) float f32x4;

__device__ inline unsigned short f2bf(float f) {
    union { float f; unsigned int u; } v; v.f = f;
    unsigned int r = v.u + 0x7FFFu + ((v.u >> 16) & 1u);   // RNE
    return (unsigned short)(r >> 16);
}

__device__ inline bf16x8 pack8(const float4& a, const float4& b) {
    bf16x8 p;
    p[0] = (short)f2bf(a.x); p[1] = (short)f2bf(a.y);
    p[2] = (short)f2bf(a.z); p[3] = (short)f2bf(a.w);
    p[4] = (short)f2bf(b.x); p[5] = (short)f2bf(b.y);
    p[6] = (short)f2bf(b.z); p[7] = (short)f2bf(b.w);
    return p;
}

// ---------------------------------------------------------------------------
// Wt[col][d] = bf16(W[d][col])  — 128x512 bf16, once; L2/L3-resident after
// ---------------------------------------------------------------------------
__global__ void wt_kernel(const float* __restrict__ W, unsigned short* __restrict__ Wt) {
    int i = blockIdx.x * 256 + threadIdx.x;   // over 128*512
    int col = i >> 9, d = i & 511;
    Wt[i] = f2bf(W[d * KK + col]);
}

// ---------------------------------------------------------------------------
// Fused per-b kernel: logits GEMM (A direct global->reg, B LDS-dbuf)
//                     -> tanh+weighted k-reduce -> softmax -> Pt[s]*tfh[b,s,:]
// 512 threads = 8 waves; wave w owns s-rows w*32..w*32+31.
// ---------------------------------------------------------------------------
__global__ __launch_bounds__(512, 4) void fused_kernel(
    const float* __restrict__ tfh,           // [BB,SS,DD]
    const unsigned short* __restrict__ Wt,   // [KK][DD] bf16
    const float* __restrict__ wpk,           // [KK]
    const float* __restrict__ bias,          // [SS]
    float* __restrict__ out)                 // [BB,SS,DD]
{
    __shared__ unsigned short Bs[2][KK][40];
    __shared__ float logit_s[256];
    __shared__ float Pt[SS];
    __shared__ float wpart[8];

    int tid = threadIdx.x;
    int w   = tid >> 6;        // wave 0..7
    int l   = tid & 63;
    int l15 = l & 15;
    int g   = l >> 4;
    int b   = blockIdx.x;
    const float* Ab = tfh + (size_t)b * SS * DD;

    // A-fragment addressing: this thread's two rows, 8 contiguous d at g*8
    int row0 = w * 32 + l15;
    int row1 = row0 + 16;
    bool v0 = row0 < SS, v1 = row1 < SS;
    const float* a0 = Ab + (size_t)row0 * DD + g * 8;
    const float* a1 = Ab + (size_t)row1 * DD + g * 8;

    // B staging: thread covers krow=tid>>2, 8 d-cols at (tid&3)*8
    int brow = tid >> 2;
    int bcol = (tid & 3) * 8;
    const unsigned short* bp = Wt + (size_t)brow * DD + bcol;

    f32x4 acc[2][8];
    #pragma unroll
    for (int m = 0; m < 2; ++m)
        #pragma unroll
        for (int n = 0; n < 8; ++n) acc[m][n] = (f32x4){0.f, 0.f, 0.f, 0.f};

    float wv[8];
    #pragma unroll
    for (int n = 0; n < 8; ++n) wv[n] = wpk[n * 16 + l15];

    const float4 fz = make_float4(0.f, 0.f, 0.f, 0.f);

    // prologue: A tile 0 -> regs, B tile 0 -> LDS
    float4 cA00 = v0 ? *(const float4*)(a0)     : fz;
    float4 cA01 = v0 ? *(const float4*)(a0 + 4) : fz;
    float4 cA10 = v1 ? *(const float4*)(a1)     : fz;
    float4 cA11 = v1 ? *(const float4*)(a1 + 4) : fz;
    *(bf16x8*)&Bs[0][brow][bcol] = *(const bf16x8*)(bp);
    __syncthreads();

    #pragma unroll 2
    for (int t = 0; t < 16; ++t) {
        int p = t & 1;
        float4 nA00, nA01, nA10, nA11;
        bf16x8 nB;
        if (t < 15) {      // issue next tile's loads early (regs)
            int d = (t + 1) * 32;
            nA00 = v0 ? *(const float4*)(a0 + d)     : fz;
            nA01 = v0 ? *(const float4*)(a0 + d + 4) : fz;
            nA10 = v1 ? *(const float4*)(a1 + d)     : fz;
            nA11 = v1 ? *(const float4*)(a1 + d + 4) : fz;
            nB   = *(const bf16x8*)(bp + d);
        }
        bf16x8 af0 = pack8(cA00, cA01);
        bf16x8 af1 = pack8(cA10, cA11);
        #pragma unroll
        for (int n = 0; n < 8; ++n) {
            bf16x8 bfv = *(const bf16x8*)&Bs[p][n * 16 + l15][g * 8];
            acc[0][n] = __builtin_amdgcn_mfma_f32_16x16x32_bf16(af0, bfv, acc[0][n], 0, 0, 0);
            acc[1][n] = __builtin_amdgcn_mfma_f32_16x16x32_bf16(af1, bfv, acc[1][n], 0, 0, 0);
        }
        if (t < 15) *(bf16x8*)&Bs[p ^ 1][brow][bcol] = nB;
        __syncthreads();
        cA00 = nA00; cA01 = nA01; cA10 = nA10; cA11 = nA11;
    }

    // --- epilogue: tanh, weight, reduce over k; logits into LDS ---
    float rs[2][4];
    #pragma unroll
    for (int m = 0; m < 2; ++m)
        #pragma unroll
        for (int r = 0; r < 4; ++r) rs[m][r] = 0.f;
    #pragma unroll
    for (int m = 0; m < 2; ++m)
        #pragma unroll
        for (int n = 0; n < 8; ++n)
            #pragma unroll
            for (int r = 0; r < 4; ++r)
                rs[m][r] += tanhf(acc[m][n][r]) * wv[n];
    #pragma unroll
    for (int m = 0; m < 2; ++m)
        #pragma unroll
        for (int r = 0; r < 4; ++r) {
            float v = rs[m][r];
            v += __shfl_xor(v, 1, 64);
            v += __shfl_xor(v, 2, 64);
            v += __shfl_xor(v, 4, 64);
            v += __shfl_xor(v, 8, 64);
            rs[m][r] = v;
        }
    if (l15 == 0) {
        #pragma unroll
        for (int m = 0; m < 2; ++m)
            #pragma unroll
            for (int r = 0; r < 4; ++r) {
                int srow = w * 32 + m * 16 + g * 4 + r;
                if (srow < SS) logit_s[srow] = rs[m][r] + bias[srow];
            }
    }
    __syncthreads();

    // --- softmax over 200 entries ---
    float v = (tid < SS) ? logit_s[tid] : -INFINITY;
    float m = v;
    #pragma unroll
    for (int off = 32; off > 0; off >>= 1) m = fmaxf(m, __shfl_xor(m, off, 64));
    if (l == 0) wpart[w] = m;
    __syncthreads();
    m = -INFINITY;
    #pragma unroll
    for (int i = 0; i < 8; ++i) m = fmaxf(m, wpart[i]);
    float e = (tid < SS) ? expf(v - m) : 0.f;
    float ssum = e;
    #pragma unroll
    for (int off = 32; off > 0; off >>= 1) ssum += __shfl_xor(ssum, off, 64);
    __syncthreads();
    if (l == 0) wpart[w] = ssum;
    __syncthreads();
    ssum = 0.f;
    #pragma unroll
    for (int i = 0; i < 8; ++i) ssum += wpart[i];
    if (tid < SS) Pt[tid] = e / ssum;
    __syncthreads();

    // --- phase 3: out[s,:] = Pt[s] * tfh[b,s,:]  (re-read hits L3) ---
    const float4* src = (const float4*)Ab;
    float4*       dst = (float4*)(out + (size_t)b * SS * DD);
    const int n4 = SS * DD / 4;   // 25600; 128 float4 per s-row
    for (int i = tid; i < n4; i += 512) {
        float p = Pt[i >> 7];
        float4 x = src[i];
        x.x *= p; x.y *= p; x.z *= p; x.w *= p;
        dst[i] = x;
    }
}

// ---------------------------------------------------------------------------
extern "C" void kernel_launch(void* const* d_in, const int* in_sizes, int n_in,
                              void* d_out, int out_size, void* d_ws, size_t ws_size,
                              hipStream_t stream) {
    const float* tfh   = (const float*)d_in[1];
    const float* wVt1  = (const float*)d_in[7];
    const float* wp1   = (const float*)d_in[8];
    const float* bias1 = (const float*)d_in[9];
    float* out = (float*)d_out;

    unsigned short* Wt = (unsigned short*)d_ws;   // 128KB

    wt_kernel<<<KK * DD / 256, 256, 0, stream>>>(wVt1, Wt);
    fused_kernel<<<BB, 512, 0, stream>>>(tfh, Wt, wp1 + KK, bias1, out);
}